// Round 12
// baseline (55.088 us; speedup 1.0000x reference)
//
#include <hip/hip_runtime.h>
#include <math.h>

#pragma clang fp contract(off)

#define BATCH 8
#define N_PROP 8000
#define N_GT 256
#define N_ALL 8256
#define PRE_NMS 1000
#define DETS 300
#define IMG 800.0f
#define DW_CLIP 4.135166556742356f
#define NWORDS 32   // 1000 bits -> 32 u32 words
#define NBINS 8192
#define BIN_SCALE 8192.0f
#define PREP_PER_BATCH 65   // ceil(8256/128) 128-proposal blocks
#define SEL_BLOCKS 8

// Correctly-rounded f32 exp/log via double — matches the numpy reference
// transcendentals bit-for-bit (absmax 0.0 since R1). Do not touch.
__device__ __forceinline__ float exf(float x) { return (float)exp((double)x); }
__device__ __forceinline__ float lgf(float x) { return (float)log((double)x); }

__device__ __forceinline__ int score_bin(float s) {
  int b = (int)(s * BIN_SCALE);
  return (b < 0) ? 0 : (b > NBINS - 1 ? NBINS - 1 : b);
}

// bx[] LDS slot swizzle. [validated R3: SQ_LDS_BANK_CONFLICT 3.5M -> 221K]
__device__ __forceinline__ int bxp(int j) { return j ^ ((j >> 5) & 7); }

// Named scalars for the serial scan (R5-validated: arrays scratch-demote in
// complex kernels; named scalars stay in VGPRs).
#define REP32(F) F(0) F(1) F(2) F(3) F(4) F(5) F(6) F(7) F(8) F(9) F(10) \
  F(11) F(12) F(13) F(14) F(15) F(16) F(17) F(18) F(19) F(20) F(21) F(22) \
  F(23) F(24) F(25) F(26) F(27) F(28) F(29) F(30) F(31)

// R12: scan drops LDS staging entirely — direct-global window reads into
// named scalars with one-window-ahead prefetch (R0's prefetch pattern +
// R5's named-scalar register residency).  Staging bought re-use that the
// R8 early-exit removed: each row-word is consumed exactly once.

// K1: fused [select_rank (idx<8)] || [prep match+labels+encode (idx>=8)].
// [structure validated R9; single-exp softmax validated R11: absmax 0.0]
__global__ void __launch_bounds__(1024)
fused_select_prep_kernel(const float* __restrict__ prop,
                         const float* __restrict__ gt,
                         const float* __restrict__ logits,
                         const float* __restrict__ breg,
                         float* __restrict__ out_labels,
                         float* __restrict__ out_regt,
                         float* __restrict__ top_s,
                         float* __restrict__ top_b) {
  const int idx = blockIdx.x;
  const int tid = threadIdx.x;
  __shared__ __align__(16) float ssc[N_ALL];          // 33.0 KB
  __shared__ unsigned hist[NBINS];                    // 32.0 KB
  __shared__ __align__(16) float sc2[N_ALL];          // 33.0 KB
  __shared__ unsigned short idx2[N_ALL];              // 16.5 KB
  __shared__ __align__(16) float4 gsh[N_GT];          //  4.0 KB
  __shared__ int s_wt[16], s_wx[16];
  __shared__ int s_T, s_Nc;
  __shared__ __align__(16) float4 gsh4[N_GT];         //  4.0 KB (prep)
  __shared__ float s_best[128];
  __shared__ int s_bi[128];

  if (idx < SEL_BLOCKS) {
    // ================= SELECT ROLE =================
    const int b = idx;
    const int lane = tid & 63, wid = tid >> 6;

    if (tid < N_GT) gsh[tid] = ((const float4*)(gt + (size_t)b * N_GT * 4))[tid];

    // thresholded scores, SINGLE-EXP softmax (bit-exact; validated R11)
    for (int k = tid; k < N_ALL; k += 1024) {
      const float2 lg = *(const float2*)(logits + ((size_t)b * N_ALL + k) * 2);
      const float d = lg.x - lg.y;
      const float u = exf((d <= 0.0f) ? d : (-d));
      const float s = (d <= 0.0f) ? (1.0f / (u + 1.0f)) : (u / (1.0f + u));
      ssc[k] = (s > 0.05f) ? s : -1.0f;
    }
    #pragma unroll
    for (int i = 0; i < NBINS / 1024; ++i) hist[tid + i * 1024] = 0u;
    __syncthreads();
    for (int k = tid; k < N_ALL; k += 1024)
      atomicAdd(&hist[score_bin(ssc[k])], 1u);
    __syncthreads();

    // thread tid owns bins [tid*8, tid*8+8)
    int local = 0;
    #pragma unroll
    for (int i = 0; i < NBINS / 1024; ++i) local += (int)hist[tid * (NBINS / 1024) + i];

    int incl = local;                       // suffix-inclusive within wave
    #pragma unroll
    for (int off = 1; off < 64; off <<= 1) {
      const int u = __shfl_down(incl, off);
      incl += (lane + off < 64) ? u : 0;
    }
    if (lane == 0) s_wt[wid] = incl;
    __syncthreads();
    if (tid < 16) {                         // suffix across the 16 waves
      const int v = s_wt[tid];
      int inc2 = v;
      #pragma unroll
      for (int off = 1; off < 16; off <<= 1) {
        const int u = __shfl_down(inc2, off);
        inc2 += (tid + off < 16) ? u : 0;
      }
      s_wx[tid] = inc2 - v;
    }
    __syncthreads();
    const int sa = (incl - local) + s_wx[wid];

    {
      int above = sa;
      const int hi = tid * (NBINS / 1024) + (NBINS / 1024) - 1;
      #pragma unroll
      for (int i = 0; i < NBINS / 1024; ++i) {
        const int bin = hi - i;
        const int c = (int)hist[bin];
        if (above < PRE_NMS && above + c >= PRE_NMS) { s_T = bin; s_Nc = above + c; }
        hist[bin] = (unsigned)above;
        above += c;
      }
    }
    __syncthreads();
    const int T = s_T;
    const int Nc = s_Nc;

    for (int k = tid; k < N_ALL; k += 1024) {
      const float v = ssc[k];
      const int bb = score_bin(v);
      if (bb >= T) {
        const int slot = (int)atomicAdd(&hist[bb], 1u);
        sc2[slot] = v;
        idx2[slot] = (unsigned short)k;
      }
    }
    __syncthreads();

    // exact rank + lazy decode of winning boxes (R7/R9-validated bit-exact)
    float* tsb = top_s + (size_t)b * PRE_NMS;
    float4* tbb = (float4*)top_b + (size_t)b * PRE_NMS;
    for (int s = tid; s < Nc; s += 1024) {
      const float my = sc2[s];
      const int myb = score_bin(my);
      const int myi = (int)idx2[s];
      int gl = s;
      while (gl > 0 && score_bin(sc2[gl - 1]) == myb) --gl;
      int rank = gl;
      for (int k2 = gl; k2 < Nc; ++k2) {
        const float v = sc2[k2];
        if (score_bin(v) != myb) break;
        if (k2 == s) continue;
        rank += (int)((v > my) | ((v == my) & ((int)idx2[k2] < myi)));
      }
      if (rank < PRE_NMS) {
        tsb[rank] = my;
        float4 pb;
        if (myi < N_PROP) pb = ((const float4*)(prop + (size_t)b * N_PROP * 4))[myi];
        else              pb = gsh[myi - N_PROP];
        const float pw = pb.z - pb.x, ph = pb.w - pb.y;
        const float pcx = pb.x + 0.5f * pw, pcy = pb.y + 0.5f * ph;
        const float4 r = *(const float4*)(breg + (((size_t)b * N_ALL + myi) * 8 + 4));
        const float dx = r.x / 10.0f, dy = r.y / 10.0f;
        const float dw = fminf(r.z / 5.0f, DW_CLIP);
        const float dh = fminf(r.w / 5.0f, DW_CLIP);
        const float cx = dx * pw + pcx, cy = dy * ph + pcy;
        const float w2 = exf(dw) * pw, h2 = exf(dh) * ph;
        float4 bb;
        bb.x = fminf(fmaxf(cx - 0.5f * w2, 0.0f), IMG);
        bb.y = fminf(fmaxf(cy - 0.5f * h2, 0.0f), IMG);
        bb.z = fminf(fmaxf(cx + 0.5f * w2, 0.0f), IMG);
        bb.w = fminf(fmaxf(cy + 0.5f * h2, 0.0f), IMG);
        tbb[rank] = bb;
      }
    }
  } else {
    // ====== PREP ROLE: IoU match + labels + encode (terminal outputs) ======
    const int pbx = idx - SEL_BLOCKS;          // [0, 520)
    const int b = pbx / PREP_PER_BATCH;
    const int blk = pbx - b * PREP_PER_BATCH;  // [0, 65)
    {
      if (tid < N_GT)
        gsh4[tid] = ((const float4*)(gt + (size_t)b * N_GT * 4))[tid];
    }
    __syncthreads();

    const int grp = tid >> 3;              // [0, 128)
    const int gl  = tid & 7;
    const int j0b = blk * 128;
    const int j = j0b + grp;               // may exceed N_ALL in last block
    const bool jv = (j < N_ALL);

    float x1, y1, x2, y2;
    if (jv && j < N_PROP) {
      const float4 p = ((const float4*)(prop + (size_t)b * N_PROP * 4))[j];
      x1 = p.x; y1 = p.y; x2 = p.z; y2 = p.w;
    } else if (jv) {
      const float4 g = gsh4[j - N_PROP];
      x1 = g.x; y1 = g.y; x2 = g.z; y2 = g.w;
    } else {
      const float4 g = gsh4[0];            // inert dummy (no stores later)
      x1 = g.x; y1 = g.y; x2 = g.z; y2 = g.w;
    }
    const float areaP = (x2 - x1) * (y2 - y1);

    float best = -1.0f; int bi = gl;
    #pragma unroll 4
    for (int t = 0; t < 32; ++t) {
      const int i = gl + (t << 3);         // in-lane ascending -> '>' keeps first
      const float4 g = gsh4[i];
      const float ga = (g.z - g.x) * (g.w - g.y);
      const float w = fmaxf(fminf(g.z, x2) - fmaxf(g.x, x1), 0.0f);
      const float h = fmaxf(fminf(g.w, y2) - fmaxf(g.y, y1), 0.0f);
      const float inter = w * h;
      const float iou = inter / (ga + areaP - inter);
      if (iou > best) { best = iou; bi = i; }
    }
    #pragma unroll
    for (int m = 1; m < 8; m <<= 1) {      // (max, min-index) == first-max
      const float ov = __shfl_xor(best, m, 64);
      const int   oi = __shfl_xor(bi,  m, 64);
      if (ov > best || (ov == best && oi < bi)) { best = ov; bi = oi; }
    }
    if (gl == 0) { s_best[grp] = best; s_bi[grp] = bi; }
    __syncthreads();

    if (tid < 128) {                       // 2 waves, one proposal each
      const int j2 = j0b + tid;
      if (j2 < N_ALL) {
        const float bst = s_best[tid];
        const int   gi  = s_bi[tid];

        float px1, py1, px2, py2;
        if (j2 < N_PROP) {
          const float4 p = ((const float4*)(prop + (size_t)b * N_PROP * 4))[j2];
          px1 = p.x; py1 = p.y; px2 = p.z; py2 = p.w;
        } else {
          const float4 g = gsh4[j2 - N_PROP];
          px1 = g.x; py1 = g.y; px2 = g.z; py2 = g.w;
        }

        out_labels[(size_t)b * N_ALL + j2] = (bst < 0.5f) ? 0.0f : 1.0f;

        const float pw = px2 - px1, ph = py2 - py1;
        const float pcx = px1 + 0.5f * pw, pcy = py1 + 0.5f * ph;
        const float4 gb = gsh4[gi];
        const float gw = gb.z - gb.x, gh = gb.w - gb.y;
        const float gcx = gb.x + 0.5f * gw, gcy = gb.y + 0.5f * gh;
        float4 rt;
        rt.x = 10.0f * (gcx - pcx) / pw;
        rt.y = 10.0f * (gcy - pcy) / ph;
        rt.z = 5.0f * lgf(gw / pw);
        rt.w = 5.0f * lgf(gh / ph);
        ((float4*)out_regt)[(size_t)b * N_ALL + j2] = rt;
      }
    }
  }
}

// K2: suppression-mask build.  [validated R2 structure + R3 bxp swizzle]
__global__ void mask_kernel(const float* __restrict__ top_b,
                            unsigned* __restrict__ ws_mask) {
  const int b = blockIdx.y;
  __shared__ __align__(16) float4 bx[PRE_NMS];
  const int tid = threadIdx.x;
  {
    const float4* gb = (const float4*)top_b + (size_t)b * PRE_NMS;
    float4 v0 = gb[tid], v1 = gb[tid + 256], v2 = gb[tid + 512];
    float4 v3 = make_float4(0.f, 0.f, 0.f, 0.f);
    const bool g3 = (tid + 768) < PRE_NMS;
    if (g3) v3 = gb[tid + 768];
    bx[bxp(tid)] = v0; bx[bxp(tid + 256)] = v1; bx[bxp(tid + 512)] = v2;
    if (g3) bx[bxp(tid + 768)] = v3;
  }
  __syncthreads();
  const int idx = blockIdx.x * blockDim.x + tid;
  if (idx >= PRE_NMS * NWORDS) return;
  const int i = idx >> 5;
  const int w = idx & 31;
  const float4 bi = bx[bxp(i)];
  const float ai = (bi.z - bi.x) * (bi.w - bi.y);
  unsigned bits = 0u;
  const int j0 = w * 32;
  #pragma unroll 8
  for (int jj = 0; jj < 32; ++jj) {
    const int j = j0 + jj;
    if (j > i && j < PRE_NMS) {
      const float4 bj = bx[bxp(j)];
      const float aj = (bj.z - bj.x) * (bj.w - bj.y);
      const float ww = fmaxf(fminf(bi.z, bj.z) - fmaxf(bi.x, bj.x), 0.0f);
      const float hh = fmaxf(fminf(bi.w, bj.w) - fmaxf(bi.y, bj.y), 0.0f);
      const float inter = ww * hh;
      const float iou = inter / (ai + aj - inter);  // NaN>0.5 false
      if (iou > 0.5f) bits |= (1u << jj);
    }
  }
  ws_mask[((size_t)b * PRE_NMS + i) * NWORDS + w] = bits;
}

// K3 (R12): serial scan + det-300 selection, NO LDS STAGING.
// [recurrence validated R0-R11; early-exit R8; sw-skip R7]
// Direct-global reads into named scalars; one-window-ahead prefetch (rN)
// hides LLC latency under the SALU chain.  Each row-word is read exactly
// once, so staging had no re-use to exploit.
#define DECLA(J) unsigned rA##J;
#define DECLN(J) unsigned rN##J;
#define LOADA0(J) rA##J = gmw[(J) * NWORDS + lw];
#define LOADN(J) rN##J = gmw[(nb + (J)) * NWORDS + lw];
#define STEPJ(J) { \
  const unsigned mJ = 0u - ((sw >> (J)) & 1u); \
  const unsigned rwJ = (unsigned)__builtin_amdgcn_readlane((int)rA##J, win); \
  sw &= ~(rwJ & mJ); \
  sup |= (rA##J & mJ); }
#define COPYA(J) rA##J = rN##J;

__global__ void __launch_bounds__(256)
scan_kernel(const unsigned* __restrict__ ws_mask,
            const float* __restrict__ top_s,
            const float* __restrict__ top_b,
            float* __restrict__ out_detb,
            float* __restrict__ out_dets) {
  const int b = blockIdx.x;
  const int tid = threadIdx.x;
  __shared__ int s_npos;
  __shared__ unsigned s_flw[NWORDS];
  __shared__ int s_pref[NWORDS + 1];
  const float* ts = top_s + (size_t)b * PRE_NMS;
  const unsigned* gmw = ws_mask + (size_t)b * PRE_NMS * NWORDS;

  if (tid == 0) s_npos = 0;
  int cnt = 0;
  for (int k = tid; k < PRE_NMS; k += 256) cnt += (ts[k] > 0.0f) ? 1 : 0;
  __syncthreads();                     // s_npos zero visible
  if (cnt) atomicAdd(&s_npos, cnt);
  __syncthreads();                     // n_pos final BEFORE the serial scan
  const int n_pos = s_npos;

  unsigned keep = 0u;
  if (tid < 64) {                      // wave 0: serial greedy scan
    const int lw = tid & 31;           // word index (upper half mirrors)
    keep = (tid < NWORDS) ? ((tid == 31) ? 0xFFu : 0xFFFFFFFFu) : 0u;
    REP32(DECLA)
    REP32(DECLN)
    REP32(LOADA0)                      // window 0's rows
    int c300 = 0;
    for (int win = 0; win < 32; ++win) {
      const int nb = ((win + 1) & 31) * 32;   // wrap at end: harmless
      REP32(LOADN)                     // prefetch next window (in flight
                                       // across this window's SALU chain)
      unsigned sw = (unsigned)__builtin_amdgcn_readlane((int)keep, win);
      if (sw) {                        // wave-uniform skip of dead windows
        unsigned sup = 0u;
        REP32(STEPJ)
        keep &= ~sup;                  // one update per window
      }
      // count finalized keeps among valid rows; break once 300 are final
      int npw = n_pos - win * 32;
      npw = (npw < 0) ? 0 : (npw > 32 ? 32 : npw);
      const unsigned npmw = (npw >= 32) ? 0xFFFFFFFFu : ((1u << npw) - 1u);
      {
        const unsigned swf = (unsigned)__builtin_amdgcn_readlane((int)keep, win);
        c300 += __popc(swf & npmw);
      }
      if (c300 >= DETS) break;         // wave-uniform (scalar c300)
      REP32(COPYA)                     // advance: rA = rN
    }
  }
  __syncthreads();
  const int n_pos2 = s_npos;
  if (tid < NWORDS) {                  // wave 0 still holds keep
    const int lo = tid * 32;
    int np = n_pos2 - lo;
    np = (np < 0) ? 0 : (np > 32 ? 32 : np);
    const unsigned npm = (np >= 32) ? 0xFFFFFFFFu : ((1u << np) - 1u);
    s_flw[tid] = keep & npm;           // keep already 0 beyond bit 999
  }
  __syncthreads();
  if (tid == 0) {
    int s = 0;
    #pragma unroll
    for (int w = 0; w < NWORDS; ++w) { s_pref[w] = s; s += __popc(s_flw[w]); }
    s_pref[NWORDS] = s;
  }
  __syncthreads();
  const int tot = s_pref[NWORDS];

  for (int k = tid; k < PRE_NMS; k += 256) {
    const unsigned fw = s_flw[k >> 5];
    const int fbit = (int)((fw >> (k & 31)) & 1u);
    const int pos = s_pref[k >> 5] + __popc(fw & ((1u << (k & 31)) - 1u));
    int slot = -1; float sval = 0.0f;
    if (fbit) {
      if (pos < DETS) { slot = pos; sval = ts[k]; }
    } else {
      const int s2 = tot + (k - pos);
      if (s2 < DETS) { slot = s2; sval = -1.0f; }
    }
    if (slot >= 0) {
      out_dets[(size_t)b * DETS + slot] = sval;
      ((float4*)out_detb)[(size_t)b * DETS + slot] =
          ((const float4*)top_b)[(size_t)b * PRE_NMS + k];
    }
  }
}

extern "C" void kernel_launch(void* const* d_in, const int* in_sizes, int n_in,
                              void* d_out, int out_size, void* d_ws, size_t ws_size,
                              hipStream_t stream) {
  const float* prop   = (const float*)d_in[0];
  const float* gt     = (const float*)d_in[1];
  const float* logits = (const float*)d_in[2];
  const float* breg   = (const float*)d_in[3];

  float* out        = (float*)d_out;
  float* out_labels = out;                                   // B*N_ALL
  float* out_regt   = out + (size_t)BATCH * N_ALL;           // B*N_ALL*4
  float* out_detb   = out_regt + (size_t)BATCH * N_ALL * 4;  // B*DETS*4
  float* out_dets   = out_detb + (size_t)BATCH * DETS * 4;   // B*DETS

  float* ws_tops   = (float*)d_ws;                            // B*PRE_NMS
  float* ws_topb   = ws_tops + (size_t)BATCH * PRE_NMS;       // B*PRE_NMS*4
  unsigned* ws_mask = (unsigned*)(ws_topb + (size_t)BATCH * PRE_NMS * 4); // B*1000*32

  hipLaunchKernelGGL(fused_select_prep_kernel,
                     dim3(SEL_BLOCKS + PREP_PER_BATCH * BATCH), dim3(1024), 0, stream,
                     prop, gt, logits, breg, out_labels, out_regt,
                     ws_tops, ws_topb);
  dim3 gridm((PRE_NMS * NWORDS + 255) / 256, BATCH);
  hipLaunchKernelGGL(mask_kernel, gridm, dim3(256), 0, stream,
                     ws_topb, ws_mask);
  hipLaunchKernelGGL(scan_kernel, dim3(BATCH), dim3(256), 0, stream,
                     ws_mask, ws_tops, ws_topb, out_detb, out_dets);
}